// Round 4
// baseline (1123.931 us; speedup 1.0000x reference)
//
#include <hip/hip_runtime.h>
#include <math.h>

#define BATCH 128
#define T 250
#define D_IN 700
#define H 256
#define D_OUT 20
#define NW 4            // waves per recurrent block

// ---------------------------------------------------------------------------
// Workspace layout (fp32):
//   U     [32000][256]
//   Wi1T  [705][256]   rows 700..704 zero (gemm K-pad + prefetch overrun row)
//   C1    [257][512]   row k, lane l: {W12T[k][4l..4l+3], W11T[k][4l..4l+3]}
//   C2    [257][512]   row k, lane l: {W22T[k][4l..4l+3], Wo[l&31][k], 0,0,0}
//   row 256 of C1/C2 is all-zero (spike-list padding target)
// ---------------------------------------------------------------------------
#define N_WI1T (705 * 256)
#define N_C    (257 * 512)

__global__ void prep_k(const float* __restrict__ Wi1, const float* __restrict__ W11,
                       const float* __restrict__ W12, const float* __restrict__ W22,
                       const float* __restrict__ Wo,
                       float* __restrict__ Wi1T, float* __restrict__ C1,
                       float* __restrict__ C2) {
    int idx = blockIdx.x * 256 + threadIdx.x;
    if (idx < N_WI1T) {
        int k = idx >> 8, h = idx & 255;
        Wi1T[idx] = (k < D_IN) ? Wi1[h * D_IN + k] : 0.f;
        return;
    }
    idx -= N_WI1T;
    if (idx < N_C) {
        int k = idx >> 9, q = idx & 511;
        int l = q >> 3, jj = q & 7;
        float v = 0.f;
        if (k < H) {
            int h = 4 * l + (jj & 3);
            v = (jj < 4) ? W12[h * H + k] : W11[h * H + k];
        }
        C1[idx] = v;
        return;
    }
    idx -= N_C;
    if (idx < N_C) {
        int k = idx >> 9, q = idx & 511;
        int l = q >> 3, jj = q & 7;
        float v = 0.f;
        if (k < H) {
            if (jj < 4) v = W22[(4 * l + jj) * H + k];
            else if (jj == 4 && (l & 31) < D_OUT) v = Wo[(l & 31) * H + k];
        }
        C2[idx] = v;
    }
}

// ---------------------------------------------------------------------------
// U = x @ Wi1^T + bi1.  64-row tile, 500 blocks (~2/CU), thread = 8 rows x 8 cols.
// x tile transposed in LDS (ds_read_b128); weight rows register-prefetched.
// ---------------------------------------------------------------------------
#define GR 64
#define GK 64
__global__ __launch_bounds__(256) void gemm_u_k(const float* __restrict__ x,
                                                const float* __restrict__ Wi1T,
                                                const float* __restrict__ bi1,
                                                float* __restrict__ U) {
    __shared__ float xs[GK][GR + 4];     // 68-float rows: 16B-aligned row starts
    int tid = threadIdx.x;
    int c0 = (tid & 31) * 8;             // 32 lanes cover 256 cols
    int r0 = (tid >> 5) * 8;             // 8 groups cover 64 rows
    int m0 = blockIdx.x * GR;

    float4 a0[8], a1[8];
#pragma unroll
    for (int r = 0; r < 8; ++r) {
        a0[r] = make_float4(0.f, 0.f, 0.f, 0.f);
        a1[r] = make_float4(0.f, 0.f, 0.f, 0.f);
    }

    for (int k0 = 0; k0 < 704; k0 += GK) {
        __syncthreads();
#pragma unroll
        for (int i = 0; i < 4; ++i) {
            int f = tid + (i << 8);               // 1024 float4 per tile
            int r = f >> 4, c4 = (f & 15) << 2;
            int k = k0 + c4;
            float4 v = make_float4(0.f, 0.f, 0.f, 0.f);
            if (k < D_IN) v = *(const float4*)(x + (size_t)(m0 + r) * D_IN + k);
            xs[c4 + 0][r] = v.x; xs[c4 + 1][r] = v.y;
            xs[c4 + 2][r] = v.z; xs[c4 + 3][r] = v.w;
        }
        __syncthreads();

        const float* wp = Wi1T + (size_t)k0 * H + c0;
        float4 w0 = *(const float4*)(wp);
        float4 w1 = *(const float4*)(wp + 4);
        for (int k = 0; k < GK; ++k) {
            const float* wn = Wi1T + (size_t)(k0 + k + 1) * H + c0;  // row<=704 exists
            float4 nw0 = *(const float4*)(wn);
            float4 nw1 = *(const float4*)(wn + 4);
            float4 xa = *(const float4*)(&xs[k][r0]);
            float4 xb = *(const float4*)(&xs[k][r0 + 4]);
            float xv[8] = {xa.x, xa.y, xa.z, xa.w, xb.x, xb.y, xb.z, xb.w};
#pragma unroll
            for (int r = 0; r < 8; ++r) {
                float xr = xv[r];
                a0[r].x += xr * w0.x; a0[r].y += xr * w0.y;
                a0[r].z += xr * w0.z; a0[r].w += xr * w0.w;
                a1[r].x += xr * w1.x; a1[r].y += xr * w1.y;
                a1[r].z += xr * w1.z; a1[r].w += xr * w1.w;
            }
            w0 = nw0; w1 = nw1;
        }
    }

    float4 bb0 = *(const float4*)(bi1 + c0);
    float4 bb1 = *(const float4*)(bi1 + c0 + 4);
#pragma unroll
    for (int r = 0; r < 8; ++r) {
        float* up = U + (size_t)(m0 + r0 + r) * H + c0;
        float4 o0, o1;
        o0.x = a0[r].x + bb0.x; o0.y = a0[r].y + bb0.y;
        o0.z = a0[r].z + bb0.z; o0.w = a0[r].w + bb0.w;
        o1.x = a1[r].x + bb1.x; o1.y = a1[r].y + bb1.y;
        o1.z = a1[r].z + bb1.z; o1.w = a1[r].w + bb1.w;
        *(float4*)(up) = o0;
        *(float4*)(up + 4) = o1;
    }
}

// ---------------------------------------------------------------------------
// Recurrent: block = 256 threads = 4 waves, one block per batch element.
// All waves redundantly compute membrane updates + ballots (identical math);
// the spike-gather list is split 4 ways, partials combined via double-buffered
// LDS. Exactly 2 __syncthreads per step.
// ---------------------------------------------------------------------------

// Build spike list (all waves write identical content) + 64 pad rows (=256).
__device__ __forceinline__ int build_list(unsigned int* list, int lane,
                                          float sx, float sy, float sz, float sw) {
    unsigned long long m0 = __ballot(sx > 0.f);
    unsigned long long m1 = __ballot(sy > 0.f);
    unsigned long long m2 = __ballot(sz > 0.f);
    unsigned long long m3 = __ballot(sw > 0.f);
    unsigned long long below = (1ull << lane) - 1ull;
    int c0 = __popcll(m0), c1 = __popcll(m1), c2 = __popcll(m2), c3 = __popcll(m3);
    int n = c0 + c1 + c2 + c3;
    if ((m0 >> lane) & 1) list[__popcll(m0 & below)] = lane * 4;
    if ((m1 >> lane) & 1) list[c0 + __popcll(m1 & below)] = lane * 4 + 1;
    if ((m2 >> lane) & 1) list[c0 + c1 + __popcll(m2 & below)] = lane * 4 + 2;
    if ((m3 >> lane) & 1) list[c0 + c1 + c2 + __popcll(m3 & below)] = lane * 4 + 3;
    list[n + lane] = 256;                   // 64 pads -> covers all wave slices
    __builtin_amdgcn_wave_barrier();
    return n;
}

// Ring gather over this wave's slice: batches of 8 entries at lst[32b..32b+7].
// C row = 512 floats; accA += C[row][l8..l8+3], accB += C[row][l8+4..l8+7].
__device__ __forceinline__ void gather_c1(const unsigned int* lst, int m,
                                          const float* __restrict__ C,
                                          unsigned l8, float4& accA, float4& accB) {
    if (m <= 0) return;
    float4 wA[8], wB[8];
    {
        uint4 ia = *(const uint4*)(lst);
        uint4 ib = *(const uint4*)(lst + 4);
        unsigned I[8] = {ia.x, ia.y, ia.z, ia.w, ib.x, ib.y, ib.z, ib.w};
#pragma unroll
        for (int j = 0; j < 8; ++j) {
            const float* p = C + (I[j] << 9) + l8;
            wA[j] = *(const float4*)(p);
            wB[j] = *(const float4*)(p + 4);
        }
    }
    for (int b = 1; b < m; ++b) {
        uint4 ia = *(const uint4*)(lst + 32 * b);
        uint4 ib = *(const uint4*)(lst + 32 * b + 4);
        unsigned N[8] = {ia.x, ia.y, ia.z, ia.w, ib.x, ib.y, ib.z, ib.w};
#pragma unroll
        for (int j = 0; j < 8; ++j) {
            accA.x += wA[j].x; accA.y += wA[j].y; accA.z += wA[j].z; accA.w += wA[j].w;
            accB.x += wB[j].x; accB.y += wB[j].y; accB.z += wB[j].z; accB.w += wB[j].w;
            const float* p = C + (N[j] << 9) + l8;
            wA[j] = *(const float4*)(p);
            wB[j] = *(const float4*)(p + 4);
        }
    }
#pragma unroll
    for (int j = 0; j < 8; ++j) {
        accA.x += wA[j].x; accA.y += wA[j].y; accA.z += wA[j].z; accA.w += wA[j].w;
        accB.x += wB[j].x; accB.y += wB[j].y; accB.z += wB[j].z; accB.w += wB[j].w;
    }
}

__device__ __forceinline__ void gather_c2(const unsigned int* lst, int m,
                                          const float* __restrict__ C,
                                          unsigned l8, float4& accA, float& accO) {
    if (m <= 0) return;
    float4 wA[8]; float wO[8];
    {
        uint4 ia = *(const uint4*)(lst);
        uint4 ib = *(const uint4*)(lst + 4);
        unsigned I[8] = {ia.x, ia.y, ia.z, ia.w, ib.x, ib.y, ib.z, ib.w};
#pragma unroll
        for (int j = 0; j < 8; ++j) {
            const float* p = C + (I[j] << 9) + l8;
            wA[j] = *(const float4*)(p);
            wO[j] = p[4];
        }
    }
    for (int b = 1; b < m; ++b) {
        uint4 ia = *(const uint4*)(lst + 32 * b);
        uint4 ib = *(const uint4*)(lst + 32 * b + 4);
        unsigned N[8] = {ia.x, ia.y, ia.z, ia.w, ib.x, ib.y, ib.z, ib.w};
#pragma unroll
        for (int j = 0; j < 8; ++j) {
            accA.x += wA[j].x; accA.y += wA[j].y; accA.z += wA[j].z; accA.w += wA[j].w;
            accO += wO[j];
            const float* p = C + (N[j] << 9) + l8;
            wA[j] = *(const float4*)(p);
            wO[j] = p[4];
        }
    }
#pragma unroll
    for (int j = 0; j < 8; ++j) {
        accA.x += wA[j].x; accA.y += wA[j].y; accA.z += wA[j].z; accA.w += wA[j].w;
        accO += wO[j];
    }
}

__global__ __launch_bounds__(256) void recurrent_k(
    const float* __restrict__ U,
    const float* __restrict__ mem1_0, const float* __restrict__ mem2_0,
    const float* __restrict__ memo_0,
    const float* __restrict__ b11v, const float* __restrict__ b12v,
    const float* __restrict__ b22v, const float* __restrict__ bov,
    const float* __restrict__ tau_adp_h1, const float* __restrict__ tau_adp_h2,
    const float* __restrict__ tau_m_h1, const float* __restrict__ tau_m_h2,
    const float* __restrict__ tau_m_o,
    const float* __restrict__ C1, const float* __restrict__ C2,
    float* __restrict__ out)
{
    const int tid = threadIdx.x;
    const int lane = tid & 63;
    const int wv = tid >> 6;                 // 0..3
    const int bi = blockIdx.x;
    const unsigned laneOff = lane * 4;       // neuron/col base
    const unsigned l8 = lane * 8;            // C-row lane offset

    __shared__ __align__(16) unsigned int list1[320], list2[320];
    __shared__ __align__(16) float p1a[2][NW][H];   // W12 partials
    __shared__ __align__(16) float p1b[2][NW][H];   // W11 partials
    __shared__ __align__(16) float p2a[2][NW][H];   // W22 partials
    __shared__ __align__(16) float p2o[2][NW][64];  // Wo partials

    // zero the "previous step" buffers for t=0 (pb=1)
    for (int i = tid; i < NW * H; i += 256) {
        ((float*)p1b[1])[i] = 0.f;
        ((float*)p2a[1])[i] = 0.f;
    }
    __syncthreads();

    // ---- per-lane state (identical in all 4 waves): neurons h = lane*4 + j
    float4 mem1 = *(const float4*)(mem1_0 + bi * H + laneOff);
    float4 mem2 = *(const float4*)(mem2_0 + bi * H + laneOff);
    float4 b1 = make_float4(0.01f, 0.01f, 0.01f, 0.01f);
    float4 b2 = make_float4(0.01f, 0.01f, 0.01f, 0.01f);
    float4 spk1 = make_float4(0.f, 0.f, 0.f, 0.f);
    float4 spk2 = make_float4(0.f, 0.f, 0.f, 0.f);

    float4 tm1 = *(const float4*)(tau_m_h1 + laneOff);
    float4 ta1 = *(const float4*)(tau_adp_h1 + laneOff);
    float4 tm2 = *(const float4*)(tau_m_h2 + laneOff);
    float4 ta2 = *(const float4*)(tau_adp_h2 + laneOff);
    float4 al1, ro1, al2, ro2;
    al1.x = expf(-1.f / tm1.x); al1.y = expf(-1.f / tm1.y);
    al1.z = expf(-1.f / tm1.z); al1.w = expf(-1.f / tm1.w);
    ro1.x = expf(-1.f / ta1.x); ro1.y = expf(-1.f / ta1.y);
    ro1.z = expf(-1.f / ta1.z); ro1.w = expf(-1.f / ta1.w);
    al2.x = expf(-1.f / tm2.x); al2.y = expf(-1.f / tm2.y);
    al2.z = expf(-1.f / tm2.z); al2.w = expf(-1.f / tm2.w);
    ro2.x = expf(-1.f / ta2.x); ro2.y = expf(-1.f / ta2.y);
    ro2.z = expf(-1.f / ta2.z); ro2.w = expf(-1.f / ta2.w);
    float4 oma1, omr1, oma2, omr2;
    oma1.x = 1.f - al1.x; oma1.y = 1.f - al1.y; oma1.z = 1.f - al1.z; oma1.w = 1.f - al1.w;
    omr1.x = 1.f - ro1.x; omr1.y = 1.f - ro1.y; omr1.z = 1.f - ro1.z; omr1.w = 1.f - ro1.w;
    oma2.x = 1.f - al2.x; oma2.y = 1.f - al2.y; oma2.z = 1.f - al2.z; oma2.w = 1.f - al2.w;
    omr2.x = 1.f - ro2.x; omr2.y = 1.f - ro2.y; omr2.z = 1.f - ro2.z; omr2.w = 1.f - ro2.w;

    float4 b11r = *(const float4*)(b11v + laneOff);
    float4 b12r = *(const float4*)(b12v + laneOff);
    float4 b22r = *(const float4*)(b22v + laneOff);
    float4 bsum2;
    bsum2.x = b12r.x + b22r.x; bsum2.y = b12r.y + b22r.y;
    bsum2.z = b12r.z + b22r.z; bsum2.w = b12r.w + b22r.w;

    float memo = 0.f, alpha_o = 0.f, bo_r = 0.f, accv = 0.f;
    if (lane < D_OUT) {
        memo = memo_0[bi * D_OUT + lane];
        alpha_o = expf(-1.f / tau_m_o[lane]);
        bo_r = bov[lane];
    }

    const float* Up = U + (size_t)bi * T * H + laneOff;

    for (int t = 0; t < T; ++t) {
        const int buf = t & 1, pb = buf ^ 1;
        float4 u = *(const float4*)(Up);
        Up += H;

        // ===== phase 1: combine W11@sp1(t-1); layer-1 update; list1; gather C1
        float4 g11;
        {
            float4 q0 = ((const float4*)p1b[pb][0])[lane];
            float4 q1 = ((const float4*)p1b[pb][1])[lane];
            float4 q2 = ((const float4*)p1b[pb][2])[lane];
            float4 q3 = ((const float4*)p1b[pb][3])[lane];
            g11.x = q0.x + q1.x + q2.x + q3.x; g11.y = q0.y + q1.y + q2.y + q3.y;
            g11.z = q0.z + q1.z + q2.z + q3.z; g11.w = q0.w + q1.w + q2.w + q3.w;
        }
        float4 h1;
        h1.x = u.x + b11r.x + g11.x; h1.y = u.y + b11r.y + g11.y;
        h1.z = u.z + b11r.z + g11.z; h1.w = u.w + b11r.w + g11.w;
        b1.x = ro1.x * b1.x + omr1.x * spk1.x; b1.y = ro1.y * b1.y + omr1.y * spk1.y;
        b1.z = ro1.z * b1.z + omr1.z * spk1.z; b1.w = ro1.w * b1.w + omr1.w * spk1.w;
        float B1x = 0.01f + 1.8f * b1.x, B1y = 0.01f + 1.8f * b1.y;
        float B1z = 0.01f + 1.8f * b1.z, B1w = 0.01f + 1.8f * b1.w;
        mem1.x = mem1.x * al1.x + oma1.x * h1.x - B1x * spk1.x;
        mem1.y = mem1.y * al1.y + oma1.y * h1.y - B1y * spk1.y;
        mem1.z = mem1.z * al1.z + oma1.z * h1.z - B1z * spk1.z;
        mem1.w = mem1.w * al1.w + oma1.w * h1.w - B1w * spk1.w;
        spk1.x = (mem1.x - B1x > 0.f) ? 1.f : 0.f;
        spk1.y = (mem1.y - B1y > 0.f) ? 1.f : 0.f;
        spk1.z = (mem1.z - B1z > 0.f) ? 1.f : 0.f;
        spk1.w = (mem1.w - B1w > 0.f) ? 1.f : 0.f;

        int n1 = build_list(list1, lane, spk1.x, spk1.y, spk1.z, spk1.w);
        int m1 = (n1 + 31) >> 5;

        float4 a12 = make_float4(0.f, 0.f, 0.f, 0.f);
        float4 a11 = make_float4(0.f, 0.f, 0.f, 0.f);
        gather_c1(list1 + 8 * wv, m1, C1, l8, a12, a11);
        ((float4*)p1a[buf][wv])[lane] = a12;
        ((float4*)p1b[buf][wv])[lane] = a11;
        __syncthreads();                                        // barrier 1

        // ===== phase 2: combine W12@sp1(t), W22@sp2(t-1); layer-2; list2; gather C2
        float4 g12, g22;
        {
            float4 q0 = ((const float4*)p1a[buf][0])[lane];
            float4 q1 = ((const float4*)p1a[buf][1])[lane];
            float4 q2 = ((const float4*)p1a[buf][2])[lane];
            float4 q3 = ((const float4*)p1a[buf][3])[lane];
            g12.x = q0.x + q1.x + q2.x + q3.x; g12.y = q0.y + q1.y + q2.y + q3.y;
            g12.z = q0.z + q1.z + q2.z + q3.z; g12.w = q0.w + q1.w + q2.w + q3.w;
            float4 r0 = ((const float4*)p2a[pb][0])[lane];
            float4 r1 = ((const float4*)p2a[pb][1])[lane];
            float4 r2 = ((const float4*)p2a[pb][2])[lane];
            float4 r3 = ((const float4*)p2a[pb][3])[lane];
            g22.x = r0.x + r1.x + r2.x + r3.x; g22.y = r0.y + r1.y + r2.y + r3.y;
            g22.z = r0.z + r1.z + r2.z + r3.z; g22.w = r0.w + r1.w + r2.w + r3.w;
        }
        float4 h2;
        h2.x = bsum2.x + g22.x + g12.x; h2.y = bsum2.y + g22.y + g12.y;
        h2.z = bsum2.z + g22.z + g12.z; h2.w = bsum2.w + g22.w + g12.w;
        b2.x = ro2.x * b2.x + omr2.x * spk2.x; b2.y = ro2.y * b2.y + omr2.y * spk2.y;
        b2.z = ro2.z * b2.z + omr2.z * spk2.z; b2.w = ro2.w * b2.w + omr2.w * spk2.w;
        float B2x = 0.01f + 1.8f * b2.x, B2y = 0.01f + 1.8f * b2.y;
        float B2z = 0.01f + 1.8f * b2.z, B2w = 0.01f + 1.8f * b2.w;
        mem2.x = mem2.x * al2.x + oma2.x * h2.x - B2x * spk2.x;
        mem2.y = mem2.y * al2.y + oma2.y * h2.y - B2y * spk2.y;
        mem2.z = mem2.z * al2.z + oma2.z * h2.z - B2z * spk2.z;
        mem2.w = mem2.w * al2.w + oma2.w * h2.w - B2w * spk2.w;
        spk2.x = (mem2.x - B2x > 0.f) ? 1.f : 0.f;
        spk2.y = (mem2.y - B2y > 0.f) ? 1.f : 0.f;
        spk2.z = (mem2.z - B2z > 0.f) ? 1.f : 0.f;
        spk2.w = (mem2.w - B2w > 0.f) ? 1.f : 0.f;

        int n2 = build_list(list2, lane, spk2.x, spk2.y, spk2.z, spk2.w);
        int m2 = (n2 + 31) >> 5;

        float4 a22 = make_float4(0.f, 0.f, 0.f, 0.f);
        float aO = 0.f;
        gather_c2(list2 + 8 * wv, m2, C2, l8, a22, aO);
        ((float4*)p2a[buf][wv])[lane] = a22;
        p2o[buf][wv][lane] = aO;
        __syncthreads();                                        // barrier 2

        // ===== phase 3: output layer + softmax accumulation (redundant all waves)
        float gO = p2o[buf][0][lane] + p2o[buf][1][lane]
                 + p2o[buf][2][lane] + p2o[buf][3][lane];
        float o = bo_r + gO;
        memo = memo * alpha_o + (1.f - alpha_o) * o;
        if (t > 10) {
            float e = (lane < D_OUT) ? __expf(memo) : 0.f;
            float s = e;
#pragma unroll
            for (int d = 16; d >= 1; d >>= 1) s += __shfl_xor(s, d, 32);
            if (lane < D_OUT) accv += __fdividef(e, s);
        }
    }

    if (tid < D_OUT) out[bi * D_OUT + tid] = accv;
}

// ---------------------------------------------------------------------------
extern "C" void kernel_launch(void* const* d_in, const int* in_sizes, int n_in,
                              void* d_out, int out_size, void* d_ws, size_t ws_size,
                              hipStream_t stream) {
    const float* x          = (const float*)d_in[0];
    const float* mem1_0     = (const float*)d_in[1];
    const float* mem2_0     = (const float*)d_in[2];
    const float* memo_0     = (const float*)d_in[3];
    const float* Wi1        = (const float*)d_in[4];
    const float* bi1        = (const float*)d_in[5];
    const float* W11        = (const float*)d_in[6];
    const float* b11        = (const float*)d_in[7];
    const float* W12        = (const float*)d_in[8];
    const float* b12        = (const float*)d_in[9];
    const float* W22        = (const float*)d_in[10];
    const float* b22        = (const float*)d_in[11];
    const float* Wo         = (const float*)d_in[12];
    const float* bo         = (const float*)d_in[13];
    const float* tau_adp_h1 = (const float*)d_in[14];
    const float* tau_adp_h2 = (const float*)d_in[15];
    const float* tau_m_h1   = (const float*)d_in[16];
    const float* tau_m_h2   = (const float*)d_in[17];
    const float* tau_m_o    = (const float*)d_in[18];

    float* U    = (float*)d_ws;                     // [32000][256]
    float* Wi1T = U + (size_t)BATCH * T * H;        // [705][256]
    float* C1   = Wi1T + N_WI1T;                    // [257][512]
    float* C2   = C1 + N_C;                         // [257][512]

    int prep_total = N_WI1T + 2 * N_C;
    prep_k<<<(prep_total + 255) / 256, 256, 0, stream>>>(
        Wi1, W11, W12, W22, Wo, Wi1T, C1, C2);

    gemm_u_k<<<(BATCH * T) / GR, 256, 0, stream>>>(x, Wi1T, bi1, U);

    recurrent_k<<<BATCH, 256, 0, stream>>>(U, mem1_0, mem2_0, memo_0,
                                           b11, b12, b22, bo,
                                           tau_adp_h1, tau_adp_h2,
                                           tau_m_h1, tau_m_h2, tau_m_o,
                                           C1, C2, (float*)d_out);
}